// Round 3
// baseline (293.605 us; speedup 1.0000x reference)
//
#include <hip/hip_runtime.h>

// EdgewiseReduce: out[n, :] = sum over edges e with center[e]==n of feat[e, :]
// center sorted by destination. R3: single fused kernel — each wave locates
// its node's edge range with a cooperative 64-ary lower_bound (ballot-based,
// ~5 rounds for E=800k), then float4-accumulates. No offsets table, no
// atomics, d_ws unused.

#define D_FEAT 64

__device__ __forceinline__ int lower_bound64(const int* __restrict__ center,
                                             int E, int target, int lane) {
    // first index i with center[i] >= target; all lanes return same value.
    int lo = 0, hi = E;
    while (hi > lo) {
        const int range = hi - lo;
        const int s = (range + 63) >> 6;          // chunk size
        const int p = lo + lane * s;
        bool pred = false;
        if (p < hi) pred = (center[p] < target);
        const unsigned long long m = __ballot(pred);
        const int c = __popcll(m);                // pred is a prefix in lane order
        if (c == 0) {
            hi = lo;                              // answer == lo
        } else {
            const int nlo = lo + (c - 1) * s + 1; // center[nlo-1] < target
            int nhi = lo + c * s;                 // center[nhi] >= target (or == hi)
            if (nhi > hi) nhi = hi;
            lo = nlo; hi = nhi;
        }
    }
    return lo;
}

// One wave per node: 64 lanes = 4 edge-groups x 16 dim-quads.
__global__ __launch_bounds__(256) void fused_segment_sum_kernel(
        const int* __restrict__ center,
        const float* __restrict__ feat,
        float* __restrict__ out, int N, int E) {
    const int wave = threadIdx.x >> 6;
    const int lane = threadIdx.x & 63;
    const int node = blockIdx.x * 4 + wave;
    if (node >= N) return;

    const int start = lower_bound64(center, E, node, lane);
    const int end   = lower_bound64(center, E, node + 1, lane);
    const int deg   = end - start;

    const int sub = lane & 15;   // which float4 of the 64-dim row
    const int grp = lane >> 4;   // which edge subset (0..3)

    int n4 = (deg - grp + 3) >> 2;   // # float4 loads for this lane's group
    if (n4 < 0) n4 = 0;

    const float* p = feat + (size_t)(start + grp) * D_FEAT + (sub << 2);
    float4 acc = make_float4(0.f, 0.f, 0.f, 0.f);

    while (n4 >= 4) {
        const float4 a0 = *(const float4*)(p);
        const float4 a1 = *(const float4*)(p + 256);
        const float4 a2 = *(const float4*)(p + 512);
        const float4 a3 = *(const float4*)(p + 768);
        acc.x += (a0.x + a1.x) + (a2.x + a3.x);
        acc.y += (a0.y + a1.y) + (a2.y + a3.y);
        acc.z += (a0.z + a1.z) + (a2.z + a3.z);
        acc.w += (a0.w + a1.w) + (a2.w + a3.w);
        p += 1024;
        n4 -= 4;
    }
    if (n4 >= 2) {
        const float4 a0 = *(const float4*)(p);
        const float4 a1 = *(const float4*)(p + 256);
        acc.x += a0.x + a1.x;
        acc.y += a0.y + a1.y;
        acc.z += a0.z + a1.z;
        acc.w += a0.w + a1.w;
        p += 512;
        n4 -= 2;
    }
    if (n4 >= 1) {
        const float4 a0 = *(const float4*)(p);
        acc.x += a0.x; acc.y += a0.y; acc.z += a0.z; acc.w += a0.w;
    }

    // reduce across the 4 groups (lane bits 4 and 5)
    #pragma unroll
    for (int m = 32; m >= 16; m >>= 1) {
        acc.x += __shfl_xor(acc.x, m, 64);
        acc.y += __shfl_xor(acc.y, m, 64);
        acc.z += __shfl_xor(acc.z, m, 64);
        acc.w += __shfl_xor(acc.w, m, 64);
    }

    if (grp == 0) {
        *(float4*)(out + (size_t)node * D_FEAT + (sub << 2)) = acc;
    }
}

extern "C" void kernel_launch(void* const* d_in, const int* in_sizes, int n_in,
                              void* d_out, int out_size, void* d_ws, size_t ws_size,
                              hipStream_t stream) {
    const int*   edge_index = (const int*)d_in[0];   // [2, E], row 0 = center
    const float* edge_feat  = (const float*)d_in[1]; // [E, 64]
    // d_in[2] = node_types [N,1], only used for N

    const int E = in_sizes[0] / 2;
    const int N = in_sizes[2];

    fused_segment_sum_kernel<<<(N + 3) / 4, 256, 0, stream>>>(
        edge_index /* row 0 = center */, edge_feat, (float*)d_out, N, E);
}

// Round 4
// 285.895 us; speedup vs baseline: 1.0270x; 1.0270x over previous
//
#include <hip/hip_runtime.h>

// EdgewiseReduce: out[n, :] = sum over edges e with center[e]==n of feat[e, :]
// center is sorted -> build CSR offsets, then one wave per node, no atomics.
// R4: revert to R2 (best measured). R3's in-wave 64-ary search regressed
// +6.5us vs the materialized CSR table — searches serialize global-load
// latency on every wave; the CSR build kernel amortizes it once.

#define D_FEAT 64

// Kernel 1: build row offsets from sorted center array.
// offsets[n] = first edge index with center >= n; offsets[N] = E.
__global__ void build_offsets_kernel(const int* __restrict__ center,
                                     int* __restrict__ offsets,
                                     int E, int N) {
    int e = blockIdx.x * blockDim.x + threadIdx.x;
    if (e >= E) return;
    int c = center[e];
    int prev = (e == 0) ? -1 : center[e - 1];
    for (int n = prev + 1; n <= c; ++n) offsets[n] = e;
    if (e == E - 1) {
        for (int n = c + 1; n <= N; ++n) offsets[n] = E;
    }
}

// Kernel 2: one wave per node. 64 lanes = 4 edge-groups x 16 dim-quads.
// Group g's lane loads rows start+g, start+g+4, ... as float4 (16B); main
// loop keeps 4 independent loads in flight; 2-step shfl_xor cross-group
// reduce; lanes 0..15 store the node row as float4. No LDS, no atomics.
__global__ __launch_bounds__(256) void segment_sum_kernel(
        const float* __restrict__ feat,
        const int* __restrict__ offsets,
        float* __restrict__ out, int N) {
    const int wave = threadIdx.x >> 6;
    const int lane = threadIdx.x & 63;
    const int node = blockIdx.x * 4 + wave;
    if (node >= N) return;

    const int start = offsets[node];
    const int deg   = offsets[node + 1] - start;
    const int sub = lane & 15;   // which float4 of the 64-dim row
    const int grp = lane >> 4;   // which edge subset (0..3)

    int n4 = (deg - grp + 3) >> 2;   // # float4 loads for this lane's group
    if (n4 < 0) n4 = 0;

    const float* p = feat + (size_t)(start + grp) * D_FEAT + (sub << 2);
    float4 acc = make_float4(0.f, 0.f, 0.f, 0.f);

    while (n4 >= 4) {
        const float4 a0 = *(const float4*)(p);
        const float4 a1 = *(const float4*)(p + 256);
        const float4 a2 = *(const float4*)(p + 512);
        const float4 a3 = *(const float4*)(p + 768);
        acc.x += (a0.x + a1.x) + (a2.x + a3.x);
        acc.y += (a0.y + a1.y) + (a2.y + a3.y);
        acc.z += (a0.z + a1.z) + (a2.z + a3.z);
        acc.w += (a0.w + a1.w) + (a2.w + a3.w);
        p += 1024;
        n4 -= 4;
    }
    if (n4 >= 2) {
        const float4 a0 = *(const float4*)(p);
        const float4 a1 = *(const float4*)(p + 256);
        acc.x += a0.x + a1.x;
        acc.y += a0.y + a1.y;
        acc.z += a0.z + a1.z;
        acc.w += a0.w + a1.w;
        p += 512;
        n4 -= 2;
    }
    if (n4 >= 1) {
        const float4 a0 = *(const float4*)(p);
        acc.x += a0.x; acc.y += a0.y; acc.z += a0.z; acc.w += a0.w;
    }

    #pragma unroll
    for (int m = 32; m >= 16; m >>= 1) {
        acc.x += __shfl_xor(acc.x, m, 64);
        acc.y += __shfl_xor(acc.y, m, 64);
        acc.z += __shfl_xor(acc.z, m, 64);
        acc.w += __shfl_xor(acc.w, m, 64);
    }

    if (grp == 0) {
        *(float4*)(out + (size_t)node * D_FEAT + (sub << 2)) = acc;
    }
}

extern "C" void kernel_launch(void* const* d_in, const int* in_sizes, int n_in,
                              void* d_out, int out_size, void* d_ws, size_t ws_size,
                              hipStream_t stream) {
    const int*   edge_index = (const int*)d_in[0];   // [2, E], row 0 = center
    const float* edge_feat  = (const float*)d_in[1]; // [E, 64]
    // d_in[2] = node_types [N,1], only used for N

    const int E = in_sizes[0] / 2;
    const int N = in_sizes[2];

    const int* center = edge_index;          // row 0
    int* offsets = (int*)d_ws;               // N+1 ints of scratch

    build_offsets_kernel<<<(E + 255) / 256, 256, 0, stream>>>(center, offsets, E, N);
    segment_sum_kernel<<<(N + 3) / 4, 256, 0, stream>>>(edge_feat, offsets,
                                                        (float*)d_out, N);
}